// Round 1
// baseline (795.494 us; speedup 1.0000x reference)
//
#include <hip/hip_runtime.h>

// Problem constants (match reference): B=256, S=1024, E=256, C=4, NB=4
#define BB 256
#define SS 1024
#define EE 256
#define CC 4

// One block per (batch, branch). 256 threads = 4 waves.
//   tid = sl*64 + e4 :  e4 in [0,64) owns float4 at embed offset e4*4,
//                       sl in [0,4) owns seq positions s = sl, sl+4, sl+8, ...
// Phase 1: mean-pool over S (coalesced float4 streaming, 2 accumulators).
// Phase 2: LDS combine of the 4 seq-slices.
// Phase 3: wave 0 computes the 4 class dots + bias + relu + argmax, votes
//          via atomicAdd of exact 0.25f into the (memset-zeroed) output.
__global__ __launch_bounds__(256) void pool_vote_kernel(
    const float* __restrict__ x0, const float* __restrict__ x1,
    const float* __restrict__ x2, const float* __restrict__ x3,
    const float* __restrict__ W, const float* __restrict__ bias,
    float* __restrict__ out)
{
    const int bn = blockIdx.x;
    const int b  = bn >> 2;
    const int n  = bn & 3;
    const float* __restrict__ x =
        (n == 0) ? x0 : (n == 1) ? x1 : (n == 2) ? x2 : x3;

    const int tid = threadIdx.x;
    const int e4  = tid & 63;   // float4 column
    const int sl  = tid >> 6;   // seq slice (0..3)

    // base element offset: batch slab + first seq row of this slice + embed col
    const size_t base = (size_t)b * ((size_t)SS * EE)
                      + (size_t)sl * EE
                      + (size_t)(e4 << 2);
    const float4* __restrict__ p = (const float4*)(x + base);
    // stepping s by 4 advances 4*EE floats = EE float4s
    const size_t stride = EE;

    float4 a0 = make_float4(0.f, 0.f, 0.f, 0.f);
    float4 a1 = make_float4(0.f, 0.f, 0.f, 0.f);
    #pragma unroll 4
    for (int i = 0; i < SS / 4; i += 2) {
        float4 v0 = p[(size_t)i * stride];
        float4 v1 = p[(size_t)(i + 1) * stride];
        a0.x += v0.x; a0.y += v0.y; a0.z += v0.z; a0.w += v0.w;
        a1.x += v1.x; a1.y += v1.y; a1.z += v1.z; a1.w += v1.w;
    }
    float4 acc;
    acc.x = a0.x + a1.x; acc.y = a0.y + a1.y;
    acc.z = a0.z + a1.z; acc.w = a0.w + a1.w;

    __shared__ float4 red[256];
    red[tid] = acc;
    __syncthreads();

    if (tid < 64) {
        float4 s0 = red[tid];
        float4 s1 = red[tid + 64];
        float4 s2 = red[tid + 128];
        float4 s3 = red[tid + 192];
        const float inv = 1.0f / (float)SS;
        float4 pool;
        pool.x = (s0.x + s1.x + s2.x + s3.x) * inv;
        pool.y = (s0.y + s1.y + s2.y + s3.y) * inv;
        pool.z = (s0.z + s1.z + s2.z + s3.z) * inv;
        pool.w = (s0.w + s1.w + s2.w + s3.w) * inv;

        // per-lane partial dot for each of the 4 classes
        const float4* __restrict__ W4 = (const float4*)W;  // [C][64] float4
        float d0, d1, d2, d3;
        {
            float4 w0 = W4[0 * 64 + tid];
            float4 w1 = W4[1 * 64 + tid];
            float4 w2 = W4[2 * 64 + tid];
            float4 w3 = W4[3 * 64 + tid];
            d0 = pool.x * w0.x + pool.y * w0.y + pool.z * w0.z + pool.w * w0.w;
            d1 = pool.x * w1.x + pool.y * w1.y + pool.z * w1.z + pool.w * w1.w;
            d2 = pool.x * w2.x + pool.y * w2.y + pool.z * w2.z + pool.w * w2.w;
            d3 = pool.x * w3.x + pool.y * w3.y + pool.z * w3.z + pool.w * w3.w;
        }
        // 64-lane butterfly reduction (tid<64 is exactly wave 0)
        #pragma unroll
        for (int off = 32; off >= 1; off >>= 1) {
            d0 += __shfl_down(d0, off, 64);
            d1 += __shfl_down(d1, off, 64);
            d2 += __shfl_down(d2, off, 64);
            d3 += __shfl_down(d3, off, 64);
        }

        if (tid == 0) {
            float l0 = fmaxf(d0 + bias[0], 0.f);
            float l1 = fmaxf(d1 + bias[1], 0.f);
            float l2 = fmaxf(d2 + bias[2], 0.f);
            float l3 = fmaxf(d3 + bias[3], 0.f);
            // first-max-wins argmax (matches jnp.argmax tie semantics,
            // incl. the all-negative -> all-relu-zero -> pred 0 case)
            int pred = 0; float best = l0;
            if (l1 > best) { best = l1; pred = 1; }
            if (l2 > best) { best = l2; pred = 2; }
            if (l3 > best) { best = l3; pred = 3; }
            atomicAdd(&out[b * CC + pred], 0.25f);  // exact in fp32
        }
    }
}

extern "C" void kernel_launch(void* const* d_in, const int* in_sizes, int n_in,
                              void* d_out, int out_size, void* d_ws, size_t ws_size,
                              hipStream_t stream) {
    const float* x_acc  = (const float*)d_in[0];
    const float* x_bvp  = (const float*)d_in[1];
    const float* x_eda  = (const float*)d_in[2];
    const float* x_temp = (const float*)d_in[3];
    const float* W      = (const float*)d_in[4];
    const float* bias   = (const float*)d_in[5];
    float* out = (float*)d_out;

    // d_out is poisoned 0xAA before every timed launch; zero it (capture-safe).
    hipMemsetAsync(out, 0, (size_t)out_size * sizeof(float), stream);

    pool_vote_kernel<<<dim3(BB * 4), dim3(256), 0, stream>>>(
        x_acc, x_bvp, x_eda, x_temp, W, bias, out);
}